// Round 1
// baseline (131.390 us; speedup 1.0000x reference)
//
#include <hip/hip_runtime.h>
#include <hip/hip_bf16.h>
#include <cstdint>
#include <cstddef>

#define NB 2048
#define NT 200
#define ND 64
#define NH1 128
#define NH2 64

typedef __bf16 bf16x8 __attribute__((ext_vector_type(8)));
typedef float f32x4 __attribute__((ext_vector_type(4)));

#define MFMA16(A, Bv, C) __builtin_amdgcn_mfma_f32_16x16x32_bf16((A), (Bv), (C), 0, 0, 0)

__device__ __forceinline__ unsigned short bf16_rne(float f) {
    unsigned int u = __builtin_bit_cast(unsigned int, f);
    u += 0x7FFFu + ((u >> 16) & 1u);
    return (unsigned short)(u >> 16);
}
__device__ __forceinline__ float bf16_f32(unsigned short h) {
    unsigned int u = ((unsigned int)h) << 16;
    return __builtin_bit_cast(float, u);
}

union BF8u { unsigned short u[8]; bf16x8 v; };

// Precompute: Qp = W1q + W1d, Ab = W1k - W1d (fp32), W2 transposed + bf16-split.
__global__ void prep_kernel(const float* __restrict__ W1, const float* __restrict__ W2,
                            float* __restrict__ Qp, float* __restrict__ Ab,
                            unsigned short* __restrict__ W2thi, unsigned short* __restrict__ W2tlo) {
    int tid = blockIdx.x * blockDim.x + threadIdx.x;
    if (tid < 64 * NH1) {
        int c = tid >> 7, j = tid & (NH1 - 1);
        float wq = W1[c * NH1 + j];
        float wk = W1[(64 + c) * NH1 + j];
        float wd = W1[(128 + c) * NH1 + j];
        Qp[tid] = wq + wd;
        Ab[tid] = wk - wd;
        // W2t[j][k] = W2[k][j], split hi/lo bf16.  (tid = jj*128 + k)
        int jj = tid >> 7, k = tid & 127;
        float v = W2[k * NH2 + jj];
        unsigned short hi = bf16_rne(v);
        float lo = v - bf16_f32(hi);
        W2thi[tid] = hi;
        W2tlo[tid] = bf16_rne(lo);
    }
}

__global__ __launch_bounds__(256, 2)
void attn_main(const float* __restrict__ query, const float* __restrict__ key,
               const float* __restrict__ value, const int* __restrict__ mask,
               const float* __restrict__ W1, const float* __restrict__ b1,
               const float* __restrict__ b2, const float* __restrict__ Wo,
               const float* __restrict__ Qp, const float* __restrict__ Ab,
               const unsigned short* __restrict__ W2thi, const unsigned short* __restrict__ W2tlo,
               float* __restrict__ out)
{
    __shared__ float q_s[ND];
    __shared__ float qh_s[NH1];
    __shared__ unsigned short khi_s[64][72];     // stride 144B -> banks t*4 mod 32, 2-way free
    __shared__ unsigned short klo_s[64][72];
    __shared__ unsigned short h1hi_s[64][136];   // stride 272B -> banks t*4 mod 32, 2-way free
    __shared__ unsigned short h1lo_s[64][136];
    __shared__ float scores_s[208];
    __shared__ float red_s[16][68];
    __shared__ float wred_s[4];

    const int b = blockIdx.x;
    const int tid = threadIdx.x;
    const int lane = tid & 63;
    const int wave = tid >> 6;
    const int jn = lane & 15;
    const int g8 = (lane >> 4) * 8;

    if (tid < ND) q_s[tid] = query[(size_t)b * ND + tid];
    __syncthreads();

    if (tid < 208) scores_s[tid] = 0.f;
    if (tid < NH1) {
        float a = b1[tid];
        #pragma unroll 8
        for (int c = 0; c < ND; ++c) a = fmaf(q_s[c], Qp[c * NH1 + tid], a);
        qh_s[tid] = a;
    }
    __syncthreads();

    // ---- GEMM1 B-fragments: B_b = Ab + diag(q)*W1prod, bf16-split, registers ----
    // wave owns h1 columns [32*wave, 32*wave+32): 2 N-tiles x 2 K-tiles
    bf16x8 g1_bhi[2][2], g1_blo[2][2];
    #pragma unroll
    for (int n = 0; n < 2; ++n) {
        #pragma unroll
        for (int kk = 0; kk < 2; ++kk) {
            BF8u vh, vl;
            #pragma unroll
            for (int e = 0; e < 8; ++e) {
                int c = kk * 32 + g8 + e;
                int j = wave * 32 + n * 16 + jn;
                float a = Ab[c * NH1 + j];
                float mm = W1[(192 + c) * NH1 + j];
                float v = fmaf(q_s[c], mm, a);
                unsigned short hi = bf16_rne(v);
                float rem = v - bf16_f32(hi);
                vh.u[e] = hi;
                vl.u[e] = bf16_rne(rem);
            }
            g1_bhi[n][kk] = vh.v;
            g1_blo[n][kk] = vl.v;
        }
    }
    // ---- GEMM2 B-fragments (W2t split), registers; wave owns h2 cols [16w,16w+16) ----
    bf16x8 g2_whi[4], g2_wlo[4];
    {
        const int j2 = wave * 16 + jn;
        #pragma unroll
        for (int kk = 0; kk < 4; ++kk) {
            g2_whi[kk] = *(const bf16x8*)(W2thi + j2 * NH1 + kk * 32 + g8);
            g2_wlo[kk] = *(const bf16x8*)(W2tlo + j2 * NH1 + kk * 32 + g8);
        }
    }
    const float qh0 = qh_s[wave * 32 + jn];
    const float qh1 = qh_s[wave * 32 + 16 + jn];
    const float b2j = b2[wave * 16 + jn];
    const float woj = Wo[wave * 16 + jn];

    for (int t0 = 0; t0 < NT; t0 += 64) {
        __syncthreads();
        // ---- stage k tile, bf16-split ----
        {
            const int r = tid >> 2;
            const int c0 = (tid & 3) * 16;
            const int t = t0 + r;
            float vals[16];
            if (t < NT) {
                const float* kp = key + ((size_t)b * NT + t) * ND + c0;
                #pragma unroll
                for (int i = 0; i < 4; ++i) {
                    const float4 kv = *(const float4*)(kp + i * 4);
                    vals[i*4+0] = kv.x; vals[i*4+1] = kv.y;
                    vals[i*4+2] = kv.z; vals[i*4+3] = kv.w;
                }
            } else {
                #pragma unroll
                for (int i = 0; i < 16; ++i) vals[i] = 0.f;
            }
            #pragma unroll
            for (int i = 0; i < 8; ++i) {
                unsigned short h0 = bf16_rne(vals[2*i]);
                unsigned short h1v = bf16_rne(vals[2*i+1]);
                unsigned int ph = (unsigned int)h0 | ((unsigned int)h1v << 16);
                float l0 = vals[2*i]   - bf16_f32(h0);
                float l1 = vals[2*i+1] - bf16_f32(h1v);
                unsigned int pl = (unsigned int)bf16_rne(l0) | ((unsigned int)bf16_rne(l1) << 16);
                *(unsigned int*)(&khi_s[r][c0 + 2*i]) = ph;
                *(unsigned int*)(&klo_s[r][c0 + 2*i]) = pl;
            }
        }
        __syncthreads();

        const int nmt = (t0 + 64 <= NT) ? 4 : 1;  // last tile: rows 192..207 only

        // ---- GEMM1: h1 = relu(qh + k @ B_b), split-K = 6 MFMA steps ----
        for (int mt = 0; mt < nmt; ++mt) {
            const int arow = mt * 16 + jn;
            const bf16x8 a_h0 = *(const bf16x8*)(&khi_s[arow][g8]);
            const bf16x8 a_h1 = *(const bf16x8*)(&khi_s[arow][32 + g8]);
            const bf16x8 a_l0 = *(const bf16x8*)(&klo_s[arow][g8]);
            const bf16x8 a_l1 = *(const bf16x8*)(&klo_s[arow][32 + g8]);
            #pragma unroll
            for (int n = 0; n < 2; ++n) {
                f32x4 acc = {0.f, 0.f, 0.f, 0.f};
                acc = MFMA16(a_h0, g1_bhi[n][0], acc);
                acc = MFMA16(a_h1, g1_bhi[n][1], acc);
                acc = MFMA16(a_l0, g1_bhi[n][0], acc);
                acc = MFMA16(a_l1, g1_bhi[n][1], acc);
                acc = MFMA16(a_h0, g1_blo[n][0], acc);
                acc = MFMA16(a_h1, g1_blo[n][1], acc);
                const float qhj = (n == 0) ? qh0 : qh1;
                const int j = wave * 32 + n * 16 + jn;
                #pragma unroll
                for (int r = 0; r < 4; ++r) {
                    const int tl = mt * 16 + (lane >> 4) * 4 + r;
                    float v = fmaxf(acc[r] + qhj, 0.f);
                    unsigned short hi = bf16_rne(v);
                    float rem = v - bf16_f32(hi);
                    h1hi_s[tl][j] = hi;
                    h1lo_s[tl][j] = bf16_rne(rem);
                }
            }
        }
        __syncthreads();

        // ---- GEMM2 + fused score: s_t = relu(h1@W2 + b2) . Wo ----
        for (int mt = 0; mt < nmt; ++mt) {
            const int arow = mt * 16 + jn;
            bf16x8 ahi[4], alo[4];
            #pragma unroll
            for (int kk = 0; kk < 4; ++kk) {
                ahi[kk] = *(const bf16x8*)(&h1hi_s[arow][kk * 32 + g8]);
                alo[kk] = *(const bf16x8*)(&h1lo_s[arow][kk * 32 + g8]);
            }
            f32x4 acc = {0.f, 0.f, 0.f, 0.f};
            #pragma unroll
            for (int kk = 0; kk < 4; ++kk) acc = MFMA16(ahi[kk], g2_whi[kk], acc);
            #pragma unroll
            for (int kk = 0; kk < 4; ++kk) acc = MFMA16(alo[kk], g2_whi[kk], acc);
            #pragma unroll
            for (int kk = 0; kk < 4; ++kk) acc = MFMA16(ahi[kk], g2_wlo[kk], acc);
            #pragma unroll
            for (int r = 0; r < 4; ++r) {
                float v = fmaxf(acc[r] + b2j, 0.f);
                float contrib = v * woj;
                contrib += __shfl_xor(contrib, 1);
                contrib += __shfl_xor(contrib, 2);
                contrib += __shfl_xor(contrib, 4);
                contrib += __shfl_xor(contrib, 8);
                if (jn == 0)
                    atomicAdd(&scores_s[t0 + mt * 16 + (lane >> 4) * 4 + r], contrib);
            }
        }
    }
    __syncthreads();

    // ---- mask + softmax (fp32) ----
    if (tid < 208) {
        float s = scores_s[tid];
        bool valid = (tid < NT) && (mask[(size_t)b * NT + tid] != 0);
        scores_s[tid] = valid ? s : -1e30f;
    }
    __syncthreads();
    float m = (tid < 208) ? scores_s[tid] : -1e30f;
    #pragma unroll
    for (int off = 32; off > 0; off >>= 1) m = fmaxf(m, __shfl_xor(m, off));
    if (lane == 0) wred_s[wave] = m;
    __syncthreads();
    m = fmaxf(fmaxf(wred_s[0], wred_s[1]), fmaxf(wred_s[2], wred_s[3]));
    float e = (tid < NT) ? expf(scores_s[tid] - m) : 0.f;
    __syncthreads();
    if (tid < 208) scores_s[tid] = e;
    float es = e;
    #pragma unroll
    for (int off = 32; off > 0; off >>= 1) es += __shfl_xor(es, off);
    if (lane == 0) wred_s[wave] = es;
    __syncthreads();
    const float inv = 1.f / (wred_s[0] + wred_s[1] + wred_s[2] + wred_s[3]);

    // ---- out = (attn @ V) * inv ----
    {
        const int dq = tid & 15;
        const int tg = tid >> 4;
        float a0 = 0.f, a1 = 0.f, a2 = 0.f, a3 = 0.f;
        for (int t = tg; t < NT; t += 16) {
            const float at = scores_s[t];
            const float4 v4 = *(const float4*)(value + ((size_t)b * NT + t) * ND + dq * 4);
            a0 = fmaf(at, v4.x, a0); a1 = fmaf(at, v4.y, a1);
            a2 = fmaf(at, v4.z, a2); a3 = fmaf(at, v4.w, a3);
        }
        red_s[tg][dq*4+0] = a0; red_s[tg][dq*4+1] = a1;
        red_s[tg][dq*4+2] = a2; red_s[tg][dq*4+3] = a3;
    }
    __syncthreads();
    if (tid < ND) {
        float s = 0.f;
        #pragma unroll
        for (int g = 0; g < 16; ++g) s += red_s[g][tid];
        out[(size_t)b * ND + tid] = s * inv;
    }
}

extern "C" void kernel_launch(void* const* d_in, const int* in_sizes, int n_in,
                              void* d_out, int out_size, void* d_ws, size_t ws_size,
                              hipStream_t stream) {
    const float* query = (const float*)d_in[0];
    const float* key   = (const float*)d_in[1];
    const float* value = (const float*)d_in[2];
    const int*   maskp = (const int*)d_in[3];
    const float* W1    = (const float*)d_in[4];
    const float* b1    = (const float*)d_in[5];
    const float* W2    = (const float*)d_in[6];
    const float* b2    = (const float*)d_in[7];
    const float* Wo    = (const float*)d_in[8];
    float* out = (float*)d_out;

    float* Qp = (float*)d_ws;                       // 64*128 f32
    float* Ab = Qp + 64 * NH1;                      // 64*128 f32
    unsigned short* W2thi = (unsigned short*)(Ab + 64 * NH1);  // 64*128 bf16
    unsigned short* W2tlo = W2thi + NH2 * NH1;                 // 64*128 bf16

    prep_kernel<<<32, 256, 0, stream>>>(W1, W2, Qp, Ab, W2thi, W2tlo);
    attn_main<<<NB, 256, 0, stream>>>(query, key, value, maskp, W1, b1, b2, Wo,
                                      Qp, Ab, W2thi, W2tlo, out);
}

// Round 2
// 88.340 us; speedup vs baseline: 1.4873x; 1.4873x over previous
//
#include <hip/hip_runtime.h>
#include <hip/hip_bf16.h>
#include <cstdint>
#include <cstddef>

#define NB 2048
#define NT 200
#define ND 64
#define NH1 128
#define NH2 64
#define NTP 224   // padded score length (7 tiles * 32)

typedef __bf16 bf16x8 __attribute__((ext_vector_type(8)));
typedef float f32x4 __attribute__((ext_vector_type(4)));

#define MFMA16(A, Bv, C) __builtin_amdgcn_mfma_f32_16x16x32_bf16((A), (Bv), (C), 0, 0, 0)

union BF8u { __bf16 b[8]; bf16x8 v; uint4 u4; };

// Precompute: Qp = W1q + W1d, Ab = W1k - W1d (fp32), W2 transposed + bf16-split.
__global__ void prep_kernel(const float* __restrict__ W1, const float* __restrict__ W2,
                            float* __restrict__ Qp, float* __restrict__ Ab,
                            __bf16* __restrict__ W2thi, __bf16* __restrict__ W2tlo) {
    int tid = blockIdx.x * blockDim.x + threadIdx.x;
    if (tid < 64 * NH1) {
        int c = tid >> 7, j = tid & (NH1 - 1);
        float wq = W1[c * NH1 + j];
        float wk = W1[(64 + c) * NH1 + j];
        float wd = W1[(128 + c) * NH1 + j];
        Qp[tid] = wq + wd;
        Ab[tid] = wk - wd;
        // W2t[j][k] = W2[k][j], split hi/lo bf16.  (tid = jj*128 + k)
        int jj = tid >> 7, k = tid & 127;
        float v = W2[k * NH2 + jj];
        __bf16 hi = (__bf16)v;
        W2thi[tid] = hi;
        W2tlo[tid] = (__bf16)(v - (float)hi);
    }
}

__global__ __launch_bounds__(256, 4)
void attn_main(const float* __restrict__ query, const float* __restrict__ key,
               const float* __restrict__ value, const int* __restrict__ mask,
               const float* __restrict__ W1, const float* __restrict__ b1,
               const float* __restrict__ b2, const float* __restrict__ Wo,
               const float* __restrict__ Qp, const float* __restrict__ Ab,
               const __bf16* __restrict__ W2thi, const __bf16* __restrict__ W2tlo,
               float* __restrict__ out)
{
    __shared__ float q_s[ND];
    __shared__ float qh_s[NH1];
    __shared__ __bf16 khi_s[32][72];     // 144B row stride, 16B-aligned rows
    __shared__ __bf16 klo_s[32][72];
    __shared__ __bf16 h1hi_s[32][136];   // 272B row stride, 16B-aligned rows
    __shared__ __bf16 h1lo_s[32][136];
    __shared__ float sp[4][NTP];         // per-wave score partials
    __shared__ float scores_s[256];
    __shared__ float red_s[16][68];
    __shared__ float wred_s[4];

    const int b = blockIdx.x;
    const int tid = threadIdx.x;
    const int lane = tid & 63;
    const int wave = tid >> 6;
    const int jn = lane & 15;
    const int g8 = (lane >> 4) * 8;

    if (tid < ND) q_s[tid] = query[(size_t)b * ND + tid];
    int mk = 0;
    if (tid < NT) mk = mask[(size_t)b * NT + tid];
    __syncthreads();

    if (tid < NH1) {
        float a = b1[tid];
        #pragma unroll 8
        for (int c = 0; c < ND; ++c) a = fmaf(q_s[c], Qp[c * NH1 + tid], a);
        qh_s[tid] = a;
    }

    // ---- GEMM1 B-fragments: B_b = Ab + diag(q)*W1prod, bf16-split, registers ----
    // wave owns h1 columns [32*wave, 32*wave+32): 2 N-tiles x 2 K-tiles
    bf16x8 g1_bhi[2][2], g1_blo[2][2];
    #pragma unroll
    for (int n = 0; n < 2; ++n) {
        #pragma unroll
        for (int kk = 0; kk < 2; ++kk) {
            BF8u vh, vl;
            #pragma unroll
            for (int e = 0; e < 8; ++e) {
                int c = kk * 32 + g8 + e;
                int j = wave * 32 + n * 16 + jn;
                float a = Ab[c * NH1 + j];
                float mm = W1[(192 + c) * NH1 + j];
                float v = fmaf(q_s[c], mm, a);
                __bf16 hi = (__bf16)v;
                vh.b[e] = hi;
                vl.b[e] = (__bf16)(v - (float)hi);
            }
            g1_bhi[n][kk] = vh.v;
            g1_blo[n][kk] = vl.v;
        }
    }
    // ---- GEMM2 B-fragments (W2t split), registers; wave owns h2 cols [16w,16w+16) ----
    bf16x8 g2_whi[4], g2_wlo[4];
    {
        const int j2 = wave * 16 + jn;
        #pragma unroll
        for (int kk = 0; kk < 4; ++kk) {
            g2_whi[kk] = *(const bf16x8*)(W2thi + j2 * NH1 + kk * 32 + g8);
            g2_wlo[kk] = *(const bf16x8*)(W2tlo + j2 * NH1 + kk * 32 + g8);
        }
    }
    __syncthreads();   // qh_s ready
    const float qh0 = qh_s[wave * 32 + jn];
    const float qh1 = qh_s[wave * 32 + 16 + jn];
    const float b2j = b2[wave * 16 + jn];
    const float woj = Wo[wave * 16 + jn];

    // ---- main loop over 7 t-tiles of 32 rows, k-loads prefetched one tile ahead ----
    const int r_st = tid >> 3;            // staging row 0..31
    const int c0   = (tid & 7) * 8;       // staging col 0..56
    float4 pf0, pf1;

    auto load_tile = [&](int t0) {
        const int t = t0 + r_st;
        if (t < NT) {
            const float* kp = key + ((size_t)b * NT + t) * ND + c0;
            pf0 = *(const float4*)(kp);
            pf1 = *(const float4*)(kp + 4);
        } else {
            pf0 = float4{0.f, 0.f, 0.f, 0.f};
            pf1 = float4{0.f, 0.f, 0.f, 0.f};
        }
    };
    auto store_tile = [&]() {
        float vals[8] = {pf0.x, pf0.y, pf0.z, pf0.w, pf1.x, pf1.y, pf1.z, pf1.w};
        BF8u ph, pl;
        #pragma unroll
        for (int i = 0; i < 8; ++i) {
            float v = vals[i];
            __bf16 h = (__bf16)v;
            ph.b[i] = h;
            pl.b[i] = (__bf16)(v - (float)h);
        }
        *(uint4*)(&khi_s[r_st][c0]) = ph.u4;
        *(uint4*)(&klo_s[r_st][c0]) = pl.u4;
    };

    load_tile(0);
    for (int ti = 0; ti < 7; ++ti) {
        store_tile();                       // k LDS free: GEMM1 reads done pre-syncB(ti-1)
        if (ti + 1 < 7) load_tile((ti + 1) * 32);   // in flight during GEMM1+GEMM2
        __syncthreads();                    // k ready; GEMM2(ti-1) h1 reads done

        const int t0 = ti * 32;

        // ---- GEMM1: h1 = relu(qh + k @ B_b), split-K = 6 MFMA steps ----
        #pragma unroll
        for (int mt = 0; mt < 2; ++mt) {
            const int arow = mt * 16 + jn;
            const bf16x8 a_h0 = *(const bf16x8*)(&khi_s[arow][g8]);
            const bf16x8 a_h1 = *(const bf16x8*)(&khi_s[arow][32 + g8]);
            const bf16x8 a_l0 = *(const bf16x8*)(&klo_s[arow][g8]);
            const bf16x8 a_l1 = *(const bf16x8*)(&klo_s[arow][32 + g8]);
            #pragma unroll
            for (int n = 0; n < 2; ++n) {
                f32x4 acc = {0.f, 0.f, 0.f, 0.f};
                acc = MFMA16(a_h0, g1_bhi[n][0], acc);
                acc = MFMA16(a_h1, g1_bhi[n][1], acc);
                acc = MFMA16(a_l0, g1_bhi[n][0], acc);
                acc = MFMA16(a_l1, g1_bhi[n][1], acc);
                acc = MFMA16(a_h0, g1_blo[n][0], acc);
                acc = MFMA16(a_h1, g1_blo[n][1], acc);
                const float qhj = (n == 0) ? qh0 : qh1;
                const int j = wave * 32 + n * 16 + jn;
                #pragma unroll
                for (int r = 0; r < 4; ++r) {
                    const int tl = mt * 16 + (lane >> 4) * 4 + r;
                    float v = fmaxf(acc[r] + qhj, 0.f);
                    __bf16 hi = (__bf16)v;
                    h1hi_s[tl][j] = hi;
                    h1lo_s[tl][j] = (__bf16)(v - (float)hi);
                }
            }
        }
        __syncthreads();                    // h1 ready

        // ---- GEMM2 + fused score: s_t = relu(h1@W2 + b2) . Wo ----
        #pragma unroll
        for (int mt = 0; mt < 2; ++mt) {
            const int arow = mt * 16 + jn;
            bf16x8 ahi[4], alo[4];
            #pragma unroll
            for (int kk = 0; kk < 4; ++kk) {
                ahi[kk] = *(const bf16x8*)(&h1hi_s[arow][kk * 32 + g8]);
                alo[kk] = *(const bf16x8*)(&h1lo_s[arow][kk * 32 + g8]);
            }
            f32x4 acc = {0.f, 0.f, 0.f, 0.f};
            #pragma unroll
            for (int kk = 0; kk < 4; ++kk) acc = MFMA16(ahi[kk], g2_whi[kk], acc);
            #pragma unroll
            for (int kk = 0; kk < 4; ++kk) acc = MFMA16(alo[kk], g2_whi[kk], acc);
            #pragma unroll
            for (int kk = 0; kk < 4; ++kk) acc = MFMA16(ahi[kk], g2_wlo[kk], acc);
            #pragma unroll
            for (int r = 0; r < 4; ++r) {
                float v = fmaxf(acc[r] + b2j, 0.f);
                float contrib = v * woj;
                contrib += __shfl_xor(contrib, 1);
                contrib += __shfl_xor(contrib, 2);
                contrib += __shfl_xor(contrib, 4);
                contrib += __shfl_xor(contrib, 8);
                if (jn == 0)
                    sp[wave][t0 + mt * 16 + (lane >> 4) * 4 + r] = contrib;
            }
        }
    }
    __syncthreads();   // all sp stores visible

    // ---- mask + softmax (fp32) ----
    float sc = -1e30f;
    if (tid < NT && mk != 0)
        sc = sp[0][tid] + sp[1][tid] + sp[2][tid] + sp[3][tid];
    float m = sc;
    #pragma unroll
    for (int off = 32; off > 0; off >>= 1) m = fmaxf(m, __shfl_xor(m, off));
    if (lane == 0) wred_s[wave] = m;
    __syncthreads();
    m = fmaxf(fmaxf(wred_s[0], wred_s[1]), fmaxf(wred_s[2], wred_s[3]));
    const float e = (tid < NT && mk != 0) ? __expf(sc - m) : 0.f;
    scores_s[tid] = e;
    float es = e;
    #pragma unroll
    for (int off = 32; off > 0; off >>= 1) es += __shfl_xor(es, off);
    if (lane == 0) wred_s[wave] = es;
    __syncthreads();
    const float inv = 1.f / (wred_s[0] + wred_s[1] + wred_s[2] + wred_s[3]);

    // ---- out = (attn @ V) * inv ----
    {
        const int dq = tid & 15;
        const int tg = tid >> 4;
        float a0 = 0.f, a1 = 0.f, a2 = 0.f, a3 = 0.f;
        for (int t = tg; t < NT; t += 16) {
            const float at = scores_s[t];
            const float4 v4 = *(const float4*)(value + ((size_t)b * NT + t) * ND + dq * 4);
            a0 = fmaf(at, v4.x, a0); a1 = fmaf(at, v4.y, a1);
            a2 = fmaf(at, v4.z, a2); a3 = fmaf(at, v4.w, a3);
        }
        red_s[tg][dq*4+0] = a0; red_s[tg][dq*4+1] = a1;
        red_s[tg][dq*4+2] = a2; red_s[tg][dq*4+3] = a3;
    }
    __syncthreads();
    if (tid < ND) {
        float s = 0.f;
        #pragma unroll
        for (int g = 0; g < 16; ++g) s += red_s[g][tid];
        out[(size_t)b * ND + tid] = s * inv;
    }
}

extern "C" void kernel_launch(void* const* d_in, const int* in_sizes, int n_in,
                              void* d_out, int out_size, void* d_ws, size_t ws_size,
                              hipStream_t stream) {
    const float* query = (const float*)d_in[0];
    const float* key   = (const float*)d_in[1];
    const float* value = (const float*)d_in[2];
    const int*   maskp = (const int*)d_in[3];
    const float* W1    = (const float*)d_in[4];
    const float* b1    = (const float*)d_in[5];
    const float* W2    = (const float*)d_in[6];
    const float* b2    = (const float*)d_in[7];
    const float* Wo    = (const float*)d_in[8];
    float* out = (float*)d_out;

    float* Qp = (float*)d_ws;                       // 64*128 f32
    float* Ab = Qp + 64 * NH1;                      // 64*128 f32
    __bf16* W2thi = (__bf16*)(Ab + 64 * NH1);       // 64*128 bf16
    __bf16* W2tlo = W2thi + NH2 * NH1;              // 64*128 bf16

    prep_kernel<<<32, 256, 0, stream>>>(W1, W2, Qp, Ab, W2thi, W2tlo);
    attn_main<<<NB, 256, 0, stream>>>(query, key, value, maskp, W1, b1, b2, Wo,
                                      Qp, Ab, W2thi, W2tlo, out);
}